// Round 8
// baseline (314.236 us; speedup 1.0000x reference)
//
#include <hip/hip_runtime.h>
#include <math.h>

#define N_NODES 100000
#define N_EDGES 1200000
#define F_IN 128
#define HIDDEN 64
#define CAP 40        // bucket capacity; deg ~ Poisson(12), P(deg>=40)*N ~ 1e-5
#define RB 64         // gemm rows per gemm-role block
#define NB_E 4688     // ceil(N_EDGES/256) fill blocks
#define NB_G 1563     // ceil(N_NODES/RB) gemm blocks

typedef unsigned short u16;
struct __align__(8) U16x4 { u16 x, y, z, w; };

__device__ __forceinline__ u16 f2bf(float f) {   // round-to-nearest-even
    unsigned int u = __float_as_uint(f);
    return (u16)((u + 0x7fffu + ((u >> 16) & 1u)) >> 16);
}
__device__ __forceinline__ float bf2f(u16 h) {
    return __uint_as_float((unsigned int)h << 16);
}

// ---------------- zero cnt ----------------

__global__ void zero_kernel(int* __restrict__ cnt, int n) {
    int i = blockIdx.x * blockDim.x + threadIdx.x;
    if (i < n) cnt[i] = 0;
}

// ---------------- mega kernel: fill (memory-bound) ∥ gemm1 (LDS/VALU-bound) ----------------
// bid%4==3 -> gemm role (gemm_id = bid/4), else fill role.
// gemm writes UNSCALED hn16 = bf16(x @ W1); dinv scale applied later (after fill -> cnt final).

__global__ __launch_bounds__(256) void mega_kernel(const int* __restrict__ src,
                                                   const int* __restrict__ dst,
                                                   int* __restrict__ cnt,
                                                   int* __restrict__ csr,
                                                   const float* __restrict__ x,
                                                   const float* __restrict__ W1,
                                                   u16* __restrict__ hn16) {
    __shared__ float w[F_IN * HIDDEN];  // 32 KB -> 5 blocks/CU
    const int bid = blockIdx.x;
    const int tid = threadIdx.x;

    if ((bid & 3) == 3) {
        // ---- gemm role ----
        const int g = bid >> 2;  // 0..NB_G-1 (grid sized so max bid/4 == NB_G-1)
        {
            const float4* wg = (const float4*)W1;
            float4* wl = (float4*)w;
            for (int i = tid; i < F_IN * HIDDEN / 4; i += 256) wl[i] = wg[i];
        }
        __syncthreads();
        const int tx = tid & 15;   // col group (4 cols)
        const int ty = tid >> 4;   // row group (4 rows)
        const int c = tx * 4;
        const int r0 = g * RB + ty * 4;
        int rowi[4];
#pragma unroll
        for (int rr = 0; rr < 4; ++rr) {
            int row = r0 + rr;
            rowi[rr] = row < N_NODES ? row : N_NODES - 1;  // clamp loads; store guarded
        }
        float acc[4][4] = {{0.f}};
#pragma unroll 2
        for (int kp = 0; kp < F_IN; kp += 2) {
            const float4 w0 = *(const float4*)&w[kp * HIDDEN + c];
            const float4 w1v = *(const float4*)&w[(kp + 1) * HIDDEN + c];
#pragma unroll
            for (int rr = 0; rr < 4; ++rr) {
                const float2 xv = *(const float2*)&x[(size_t)rowi[rr] * F_IN + kp];  // 16-lane broadcast
                acc[rr][0] = fmaf(xv.y, w1v.x, fmaf(xv.x, w0.x, acc[rr][0]));
                acc[rr][1] = fmaf(xv.y, w1v.y, fmaf(xv.x, w0.y, acc[rr][1]));
                acc[rr][2] = fmaf(xv.y, w1v.z, fmaf(xv.x, w0.z, acc[rr][2]));
                acc[rr][3] = fmaf(xv.y, w1v.w, fmaf(xv.x, w0.w, acc[rr][3]));
            }
        }
#pragma unroll
        for (int rr = 0; rr < 4; ++rr) {
            int row = r0 + rr;
            if (row < N_NODES) {
                U16x4 o = {f2bf(acc[rr][0]), f2bf(acc[rr][1]), f2bf(acc[rr][2]), f2bf(acc[rr][3])};
                *(U16x4*)&hn16[(size_t)row * HIDDEN + c] = o;
            }
        }
    } else {
        // ---- fill role ----
        const int fb = bid - ((bid + 1) >> 2);  // fill block id (verified mapping)
        int e = fb * 256 + tid;
        if (e < N_EDGES) {
            int d = dst[e];
            int p = atomicAdd(&cnt[d], 1);
            if (p < CAP) csr[(size_t)d * CAP + p] = src[e];
        }
    }
}

// ---------------- scale pass: hn16[row] *= rsqrt(cnt[row]+1)  (streaming, ~5us) ----------------
// 8 threads per row, 8 bf16 (16B) per thread.

__global__ void scale_kernel(u16* __restrict__ hn16, const int* __restrict__ cnt) {
    int i = blockIdx.x * blockDim.x + threadIdx.x;
    if (i >= N_NODES * 8) return;
    int row = i >> 3;
    float dd = rsqrtf((float)(cnt[row] + 1));
    uint4 v = ((uint4*)hn16)[i];
    unsigned int r[4] = {v.x, v.y, v.z, v.w};
#pragma unroll
    for (int j = 0; j < 4; ++j) {
        float lo = __uint_as_float(r[j] << 16) * dd;
        float hi = __uint_as_float(r[j] & 0xffff0000u) * dd;
        r[j] = (unsigned int)f2bf(lo) | ((unsigned int)f2bf(hi) << 16);
    }
    uint4 o = {r[0], r[1], r[2], r[3]};
    ((uint4*)hn16)[i] = o;
}

// ---------------- fused layer-1 aggregate + bias + relu + layer-2 projection ----------------
// One wave per node; lane = hidden feature. int4 index loads + 8/4/1 batched gathers.

__global__ __launch_bounds__(256) void gather1_kernel(const u16* __restrict__ hn16,
                                                      const int* __restrict__ cnt,
                                                      const int* __restrict__ csr,
                                                      const float* __restrict__ b1,
                                                      const float* __restrict__ W2,
                                                      float* __restrict__ h2n) {
    int v = (blockIdx.x * 256 + threadIdx.x) >> 6;  // 25000 blocks * 4 waves == 100000
    int lane = threadIdx.x & 63;
    if (v >= N_NODES) return;
    int deg = cnt[v];
    float dd = rsqrtf((float)(deg + 1));
    int n = deg > CAP ? CAP : deg;
    const int* idx = csr + (size_t)v * CAP;  // 160B-aligned rows
    float acc = 0.f;
    int i = 0;
    for (; i + 8 <= n; i += 8) {
        int4 q0 = *(const int4*)&idx[i];
        int4 q1 = *(const int4*)&idx[i + 4];
        float a0 = bf2f(hn16[(size_t)q0.x * HIDDEN + lane]);
        float a1 = bf2f(hn16[(size_t)q0.y * HIDDEN + lane]);
        float a2 = bf2f(hn16[(size_t)q0.z * HIDDEN + lane]);
        float a3 = bf2f(hn16[(size_t)q0.w * HIDDEN + lane]);
        float a4 = bf2f(hn16[(size_t)q1.x * HIDDEN + lane]);
        float a5 = bf2f(hn16[(size_t)q1.y * HIDDEN + lane]);
        float a6 = bf2f(hn16[(size_t)q1.z * HIDDEN + lane]);
        float a7 = bf2f(hn16[(size_t)q1.w * HIDDEN + lane]);
        acc += ((a0 + a1) + (a2 + a3)) + ((a4 + a5) + (a6 + a7));
    }
    if (i + 4 <= n) {
        int4 q = *(const int4*)&idx[i];
        float a0 = bf2f(hn16[(size_t)q.x * HIDDEN + lane]);
        float a1 = bf2f(hn16[(size_t)q.y * HIDDEN + lane]);
        float a2 = bf2f(hn16[(size_t)q.z * HIDDEN + lane]);
        float a3 = bf2f(hn16[(size_t)q.w * HIDDEN + lane]);
        acc += (a0 + a1) + (a2 + a3);
        i += 4;
    }
    for (; i < n; ++i) {
        acc += bf2f(hn16[(size_t)idx[i] * HIDDEN + lane]);
    }
    float val = dd * (acc + bf2f(hn16[(size_t)v * HIDDEN + lane])) + b1[lane];
    val = fmaxf(val, 0.f);
    float2 wv = *(const float2*)&W2[lane * 2];
    float s0 = val * wv.x;
    float s1 = val * wv.y;
#pragma unroll
    for (int m = 32; m >= 1; m >>= 1) {
        s0 += __shfl_xor(s0, m, 64);
        s1 += __shfl_xor(s1, m, 64);
    }
    if (lane == 0) {
        float2 o = {dd * s0, dd * s1};
        *(float2*)&h2n[(size_t)v * 2] = o;
    }
}

// ---------------- fused layer-2 aggregate + bias + log_softmax ----------------

__global__ void gather2_kernel(const float* __restrict__ h2n, const int* __restrict__ cnt,
                               const int* __restrict__ csr, const float* __restrict__ b2,
                               float* __restrict__ out) {
    int v = blockIdx.x * blockDim.x + threadIdx.x;
    if (v >= N_NODES) return;
    int deg = cnt[v];
    float dd = rsqrtf((float)(deg + 1));
    int n = deg > CAP ? CAP : deg;
    const int* idx = csr + (size_t)v * CAP;
    float a0 = 0.f, a1 = 0.f;
    int i = 0;
    for (; i + 8 <= n; i += 8) {
        int4 q0 = *(const int4*)&idx[i];
        int4 q1 = *(const int4*)&idx[i + 4];
        float2 h0 = *(const float2*)&h2n[(size_t)q0.x * 2];
        float2 h1 = *(const float2*)&h2n[(size_t)q0.y * 2];
        float2 h2 = *(const float2*)&h2n[(size_t)q0.z * 2];
        float2 h3 = *(const float2*)&h2n[(size_t)q0.w * 2];
        float2 h4 = *(const float2*)&h2n[(size_t)q1.x * 2];
        float2 h5 = *(const float2*)&h2n[(size_t)q1.y * 2];
        float2 h6 = *(const float2*)&h2n[(size_t)q1.z * 2];
        float2 h7 = *(const float2*)&h2n[(size_t)q1.w * 2];
        a0 += ((h0.x + h1.x) + (h2.x + h3.x)) + ((h4.x + h5.x) + (h6.x + h7.x));
        a1 += ((h0.y + h1.y) + (h2.y + h3.y)) + ((h4.y + h5.y) + (h6.y + h7.y));
    }
    if (i + 4 <= n) {
        int4 q = *(const int4*)&idx[i];
        float2 h0 = *(const float2*)&h2n[(size_t)q.x * 2];
        float2 h1 = *(const float2*)&h2n[(size_t)q.y * 2];
        float2 h2 = *(const float2*)&h2n[(size_t)q.z * 2];
        float2 h3 = *(const float2*)&h2n[(size_t)q.w * 2];
        a0 += (h0.x + h1.x) + (h2.x + h3.x);
        a1 += (h0.y + h1.y) + (h2.y + h3.y);
        i += 4;
    }
    for (; i < n; ++i) {
        float2 hv = *(const float2*)&h2n[(size_t)idx[i] * 2];
        a0 += hv.x; a1 += hv.y;
    }
    float2 hs = *(const float2*)&h2n[(size_t)v * 2];
    float v0 = dd * (a0 + hs.x) + b2[0];
    float v1 = dd * (a1 + hs.y) + b2[1];
    float m = fmaxf(v0, v1);
    float ls = m + logf(__expf(v0 - m) + __expf(v1 - m));
    float2 o = {v0 - ls, v1 - ls};
    *(float2*)&out[(size_t)v * 2] = o;
}

// ---------------- launch ----------------

extern "C" void kernel_launch(void* const* d_in, const int* in_sizes, int n_in,
                              void* d_out, int out_size, void* d_ws, size_t ws_size,
                              hipStream_t stream) {
    const float* x  = (const float*)d_in[0];
    const float* W1 = (const float*)d_in[1];
    const float* b1 = (const float*)d_in[2];
    const float* W2 = (const float*)d_in[3];
    const float* b2 = (const float*)d_in[4];
    const int* edge_index = (const int*)d_in[5];
    const int* src = edge_index;            // edge_index[0]
    const int* dst = edge_index + N_EDGES;  // edge_index[1]
    float* out = (float*)d_out;

    char* ws = (char*)d_ws;
    size_t off = 0;
    auto alloc = [&](size_t bytes) {
        void* p = ws + off;
        off = (off + bytes + 255) & ~(size_t)255;
        return p;
    };
    int*   cnt  = (int*)alloc(N_NODES * sizeof(int));
    int*   csr  = (int*)alloc((size_t)N_NODES * CAP * sizeof(int));      // 16 MB
    u16*   hn16 = (u16*)alloc((size_t)N_NODES * HIDDEN * sizeof(u16));   // 12.8 MB
    float* h2n  = (float*)alloc((size_t)N_NODES * 2 * sizeof(float));
    (void)ws_size;

    const int B = 256;
    const int NB_N = (N_NODES + B - 1) / B;   // 391

    // zero degree counters
    zero_kernel<<<NB_N, B, 0, stream>>>(cnt, N_NODES);

    // fill (CSR build) overlapped with layer-1 projection (unscaled bf16 out)
    // grid = 4*NB_G ensures gemm ids 0..NB_G-1 all present; extra fill ids guarded.
    mega_kernel<<<4 * NB_G, B, 0, stream>>>(src, dst, cnt, csr, x, W1, hn16);

    // apply dinv scale to hn16 (needs final cnt)
    scale_kernel<<<(N_NODES * 8 + B - 1) / B, B, 0, stream>>>(hn16, cnt);

    // fused layer-1 aggregation + relu + layer-2 projection (writes dinv-scaled h2n)
    gather1_kernel<<<N_NODES * 64 / B, B, 0, stream>>>(hn16, cnt, csr, b1, W2, h2n);

    // fused layer-2 aggregation + log_softmax
    gather2_kernel<<<NB_N, B, 0, stream>>>(h2n, cnt, csr, b2, out);
}

// Round 9
// 236.857 us; speedup vs baseline: 1.3267x; 1.3267x over previous
//
#include <hip/hip_runtime.h>
#include <math.h>

#define N_NODES 100000
#define N_EDGES 1200000
#define F_IN 128
#define HIDDEN 64
#define CAP 40        // bucket capacity; deg ~ Poisson(12), P(deg>=40)*N ~ 1e-5
#define RB 64         // gemm1 rows per block
#define XS_STRIDE 136 // ushort stride for xs rows (272B, 16B-aligned)
#define NRANGE 8      // dst-space partitions (== XCDs)
#define FILL_CHUNKS 256
#define FILL_BLOCKS (NRANGE * FILL_CHUNKS)  // 2048

typedef unsigned short u16;
struct __align__(8) U16x4 { u16 x, y, z, w; };

__device__ __forceinline__ u16 f2bf(float f) {   // round-to-nearest-even
    unsigned int u = __float_as_uint(f);
    return (u16)((u + 0x7fffu + ((u >> 16) & 1u)) >> 16);
}
__device__ __forceinline__ float bf2f(u16 h) {
    return __uint_as_float((unsigned int)h << 16);
}

// ---------------- zero cnt ----------------

__global__ void zero_kernel(int* __restrict__ cnt, int n) {
    int i = blockIdx.x * blockDim.x + threadIdx.x;
    if (i < n) cnt[i] = 0;
}

// ---------------- XCD-partitioned count + bucket fill ----------------
// Block bid&7 == r handles dst range [r*12500, (r+1)*12500). Under round-robin
// dispatch all such blocks share one XCD -> csr slice (2MB) and cnt slice (50KB)
// stay L2-resident; same-dst line accumulates all its edges before write-back.
// Every block streams the whole edge list (int4) and skips non-matching dsts.

__global__ __launch_bounds__(256) void fill_kernel(const int* __restrict__ src,
                                                   const int* __restrict__ dst,
                                                   int* __restrict__ cnt,
                                                   int* __restrict__ csr) {
    const int range = blockIdx.x & (NRANGE - 1);
    const int chunk = blockIdx.x >> 3;           // 0..FILL_CHUNKS-1
    const int lo = range * (N_NODES / NRANGE);   // 12500 * range
    const int hi = lo + (N_NODES / NRANGE);
    const int QUADS = N_EDGES / 4;               // 300000
    const int perq = (QUADS + FILL_CHUNKS - 1) / FILL_CHUNKS;  // 1172
    int q0 = chunk * perq;
    int q1 = q0 + perq; if (q1 > QUADS) q1 = QUADS;
    for (int q = q0 + threadIdx.x; q < q1; q += 256) {
        int4 d4 = ((const int4*)dst)[q];
        int4 s4 = ((const int4*)src)[q];
#pragma unroll
        for (int j = 0; j < 4; ++j) {
            int d = (j == 0) ? d4.x : (j == 1) ? d4.y : (j == 2) ? d4.z : d4.w;
            if (d >= lo && d < hi) {
                int s = (j == 0) ? s4.x : (j == 1) ? s4.y : (j == 2) ? s4.z : s4.w;
                int p = atomicAdd(&cnt[d], 1);
                if (p < CAP) csr[(size_t)d * CAP + p] = s;
            }
        }
    }
}

// ---------------- layer 1 GEMM + inline dinv scale: hn16 = bf16( rsqrt(cnt+1) * (x @ W1) ) ----------------
// 64x64 tile per block; thread = 4 rows x 4 cols; k unrolled x2 via bf16x2 xs reads.

__global__ __launch_bounds__(256) void gemm1_kernel(const float* __restrict__ x,
                                                    const float* __restrict__ W1,
                                                    const int* __restrict__ cnt,
                                                    u16* __restrict__ hn16) {
    __shared__ float w[F_IN * HIDDEN];      // 32 KB
    __shared__ u16 xs[RB * XS_STRIDE];      // 17 KB (bf16)
    const int tid = threadIdx.x;
    const int row0 = blockIdx.x * RB;
    {
        const float4* wg = (const float4*)W1;
        float4* wl = (float4*)w;
        for (int i = tid; i < F_IN * HIDDEN / 4; i += 256) wl[i] = wg[i];
        for (int i = tid; i < RB * F_IN / 4; i += 256) {
            int r = i / (F_IN / 4), c4 = (i % (F_IN / 4)) * 4;
            int gr = row0 + r;
            float4 v = {0.f, 0.f, 0.f, 0.f};
            if (gr < N_NODES) v = *(const float4*)&x[(size_t)gr * F_IN + c4];
            U16x4 b = {f2bf(v.x), f2bf(v.y), f2bf(v.z), f2bf(v.w)};
            *(U16x4*)&xs[r * XS_STRIDE + c4] = b;
        }
    }
    __syncthreads();
    const int tx = tid & 15;   // col group (4 cols)
    const int ty = tid >> 4;   // row group (4 rows)
    const int c = tx * 4;
    float acc[4][4] = {{0.f}};
#pragma unroll 4
    for (int kp = 0; kp < F_IN; kp += 2) {
        const float4 w0 = *(const float4*)&w[kp * HIDDEN + c];
        const float4 w1 = *(const float4*)&w[(kp + 1) * HIDDEN + c];
#pragma unroll
        for (int rr = 0; rr < 4; ++rr) {
            unsigned int u = *(const unsigned int*)&xs[(ty * 4 + rr) * XS_STRIDE + kp];
            float xlo = __uint_as_float(u << 16);
            float xhi = __uint_as_float(u & 0xffff0000u);
            acc[rr][0] = fmaf(xhi, w1.x, fmaf(xlo, w0.x, acc[rr][0]));
            acc[rr][1] = fmaf(xhi, w1.y, fmaf(xlo, w0.y, acc[rr][1]));
            acc[rr][2] = fmaf(xhi, w1.z, fmaf(xlo, w0.z, acc[rr][2]));
            acc[rr][3] = fmaf(xhi, w1.w, fmaf(xlo, w0.w, acc[rr][3]));
        }
    }
#pragma unroll
    for (int rr = 0; rr < 4; ++rr) {
        int row = row0 + ty * 4 + rr;
        if (row < N_NODES) {
            float dd = rsqrtf((float)(cnt[row] + 1));
            U16x4 o = {f2bf(acc[rr][0] * dd), f2bf(acc[rr][1] * dd),
                       f2bf(acc[rr][2] * dd), f2bf(acc[rr][3] * dd)};
            *(U16x4*)&hn16[(size_t)row * HIDDEN + c] = o;
        }
    }
}

// ---------------- fused layer-1 aggregate + bias + relu + layer-2 projection ----------------
// One wave per node; lane = hidden feature. int4 index loads + 8/4/1 batched gathers.

__global__ __launch_bounds__(256) void gather1_kernel(const u16* __restrict__ hn16,
                                                      const int* __restrict__ cnt,
                                                      const int* __restrict__ csr,
                                                      const float* __restrict__ b1,
                                                      const float* __restrict__ W2,
                                                      float* __restrict__ h2n) {
    int v = (blockIdx.x * 256 + threadIdx.x) >> 6;  // 25000 blocks * 4 waves == 100000
    int lane = threadIdx.x & 63;
    if (v >= N_NODES) return;
    int deg = cnt[v];
    float dd = rsqrtf((float)(deg + 1));
    int n = deg > CAP ? CAP : deg;
    const int* idx = csr + (size_t)v * CAP;  // 160B-aligned rows
    float acc = 0.f;
    int i = 0;
    for (; i + 8 <= n; i += 8) {
        int4 q0 = *(const int4*)&idx[i];
        int4 q1 = *(const int4*)&idx[i + 4];
        float a0 = bf2f(hn16[(size_t)q0.x * HIDDEN + lane]);
        float a1 = bf2f(hn16[(size_t)q0.y * HIDDEN + lane]);
        float a2 = bf2f(hn16[(size_t)q0.z * HIDDEN + lane]);
        float a3 = bf2f(hn16[(size_t)q0.w * HIDDEN + lane]);
        float a4 = bf2f(hn16[(size_t)q1.x * HIDDEN + lane]);
        float a5 = bf2f(hn16[(size_t)q1.y * HIDDEN + lane]);
        float a6 = bf2f(hn16[(size_t)q1.z * HIDDEN + lane]);
        float a7 = bf2f(hn16[(size_t)q1.w * HIDDEN + lane]);
        acc += ((a0 + a1) + (a2 + a3)) + ((a4 + a5) + (a6 + a7));
    }
    if (i + 4 <= n) {
        int4 q = *(const int4*)&idx[i];
        float a0 = bf2f(hn16[(size_t)q.x * HIDDEN + lane]);
        float a1 = bf2f(hn16[(size_t)q.y * HIDDEN + lane]);
        float a2 = bf2f(hn16[(size_t)q.z * HIDDEN + lane]);
        float a3 = bf2f(hn16[(size_t)q.w * HIDDEN + lane]);
        acc += (a0 + a1) + (a2 + a3);
        i += 4;
    }
    for (; i < n; ++i) {
        acc += bf2f(hn16[(size_t)idx[i] * HIDDEN + lane]);
    }
    float val = dd * (acc + bf2f(hn16[(size_t)v * HIDDEN + lane])) + b1[lane];
    val = fmaxf(val, 0.f);
    float2 wv = *(const float2*)&W2[lane * 2];
    float s0 = val * wv.x;
    float s1 = val * wv.y;
#pragma unroll
    for (int m = 32; m >= 1; m >>= 1) {
        s0 += __shfl_xor(s0, m, 64);
        s1 += __shfl_xor(s1, m, 64);
    }
    if (lane == 0) {
        float2 o = {dd * s0, dd * s1};
        *(float2*)&h2n[(size_t)v * 2] = o;
    }
}

// ---------------- fused layer-2 aggregate + bias + log_softmax ----------------

__global__ void gather2_kernel(const float* __restrict__ h2n, const int* __restrict__ cnt,
                               const int* __restrict__ csr, const float* __restrict__ b2,
                               float* __restrict__ out) {
    int v = blockIdx.x * blockDim.x + threadIdx.x;
    if (v >= N_NODES) return;
    int deg = cnt[v];
    float dd = rsqrtf((float)(deg + 1));
    int n = deg > CAP ? CAP : deg;
    const int* idx = csr + (size_t)v * CAP;
    float a0 = 0.f, a1 = 0.f;
    int i = 0;
    for (; i + 8 <= n; i += 8) {
        int4 q0 = *(const int4*)&idx[i];
        int4 q1 = *(const int4*)&idx[i + 4];
        float2 h0 = *(const float2*)&h2n[(size_t)q0.x * 2];
        float2 h1 = *(const float2*)&h2n[(size_t)q0.y * 2];
        float2 h2 = *(const float2*)&h2n[(size_t)q0.z * 2];
        float2 h3 = *(const float2*)&h2n[(size_t)q0.w * 2];
        float2 h4 = *(const float2*)&h2n[(size_t)q1.x * 2];
        float2 h5 = *(const float2*)&h2n[(size_t)q1.y * 2];
        float2 h6 = *(const float2*)&h2n[(size_t)q1.z * 2];
        float2 h7 = *(const float2*)&h2n[(size_t)q1.w * 2];
        a0 += ((h0.x + h1.x) + (h2.x + h3.x)) + ((h4.x + h5.x) + (h6.x + h7.x));
        a1 += ((h0.y + h1.y) + (h2.y + h3.y)) + ((h4.y + h5.y) + (h6.y + h7.y));
    }
    if (i + 4 <= n) {
        int4 q = *(const int4*)&idx[i];
        float2 h0 = *(const float2*)&h2n[(size_t)q.x * 2];
        float2 h1 = *(const float2*)&h2n[(size_t)q.y * 2];
        float2 h2 = *(const float2*)&h2n[(size_t)q.z * 2];
        float2 h3 = *(const float2*)&h2n[(size_t)q.w * 2];
        a0 += (h0.x + h1.x) + (h2.x + h3.x);
        a1 += (h0.y + h1.y) + (h2.y + h3.y);
        i += 4;
    }
    for (; i < n; ++i) {
        float2 hv = *(const float2*)&h2n[(size_t)idx[i] * 2];
        a0 += hv.x; a1 += hv.y;
    }
    float2 hs = *(const float2*)&h2n[(size_t)v * 2];
    float v0 = dd * (a0 + hs.x) + b2[0];
    float v1 = dd * (a1 + hs.y) + b2[1];
    float m = fmaxf(v0, v1);
    float ls = m + logf(__expf(v0 - m) + __expf(v1 - m));
    float2 o = {v0 - ls, v1 - ls};
    *(float2*)&out[(size_t)v * 2] = o;
}

// ---------------- launch ----------------

extern "C" void kernel_launch(void* const* d_in, const int* in_sizes, int n_in,
                              void* d_out, int out_size, void* d_ws, size_t ws_size,
                              hipStream_t stream) {
    const float* x  = (const float*)d_in[0];
    const float* W1 = (const float*)d_in[1];
    const float* b1 = (const float*)d_in[2];
    const float* W2 = (const float*)d_in[3];
    const float* b2 = (const float*)d_in[4];
    const int* edge_index = (const int*)d_in[5];
    const int* src = edge_index;            // edge_index[0]
    const int* dst = edge_index + N_EDGES;  // edge_index[1]
    float* out = (float*)d_out;

    char* ws = (char*)d_ws;
    size_t off = 0;
    auto alloc = [&](size_t bytes) {
        void* p = ws + off;
        off = (off + bytes + 255) & ~(size_t)255;
        return p;
    };
    int*   cnt  = (int*)alloc(N_NODES * sizeof(int));
    int*   csr  = (int*)alloc((size_t)N_NODES * CAP * sizeof(int));      // 16 MB
    u16*   hn16 = (u16*)alloc((size_t)N_NODES * HIDDEN * sizeof(u16));   // 12.8 MB
    float* h2n  = (float*)alloc((size_t)N_NODES * 2 * sizeof(float));
    (void)ws_size;

    const int B = 256;
    const int NB_N = (N_NODES + B - 1) / B;   // 391

    // CSR build: zero counters, then XCD-partitioned fill
    zero_kernel<<<NB_N, B, 0, stream>>>(cnt, N_NODES);
    fill_kernel<<<FILL_BLOCKS, B, 0, stream>>>(src, dst, cnt, csr);

    // layer 1 projection (dinv scale inline from cnt, bf16 out)
    gemm1_kernel<<<(N_NODES + RB - 1) / RB, B, 0, stream>>>(x, W1, cnt, hn16);

    // fused layer-1 aggregation + relu + layer-2 projection (writes dinv-scaled h2n)
    gather1_kernel<<<N_NODES * 64 / B, B, 0, stream>>>(hn16, cnt, csr, b1, W2, h2n);

    // fused layer-2 aggregation + log_softmax
    gather2_kernel<<<NB_N, B, 0, stream>>>(h2n, cnt, csr, b2, out);
}